// Round 7
// baseline (383.352 us; speedup 1.0000x reference)
//
#include <hip/hip_runtime.h>

#define IN_C 512
#define OUT_C 1024
#define NC2 2048
#define NEG_SLOPE 0.2f

typedef short frag8 __attribute__((ext_vector_type(8)));
typedef float f32x4 __attribute__((ext_vector_type(4)));

#define GLOAD_LDS16(g, l) __builtin_amdgcn_global_load_lds(\
    (const __attribute__((address_space(1))) void*)(g), \
    (__attribute__((address_space(3))) void*)(l), 16, 0, 0)

__device__ __forceinline__ unsigned short f2b(float f){
  unsigned u = __float_as_uint(f);
  unsigned r = (u + 0x7fffu + ((u >> 16) & 1u)) >> 16;
  return (unsigned short)r;
}
__device__ __forceinline__ unsigned encf(float f){
  unsigned u = __float_as_uint(f);
  return (u & 0x80000000u) ? ~u : (u | 0x80000000u);
}
__device__ __forceinline__ float decf(unsigned u){
  unsigned v = (u & 0x80000000u) ? (u & 0x7fffffffu) : ~u;
  return __uint_as_float(v);
}
__device__ __forceinline__ float leaky(float v){ return v >= 0.f ? v : NEG_SLOPE * v; }

// ---------------- fused preprocessing ----------------
// blocks [0,1024): WT transpose (W1|W2); [1024,2048): Wp1T; [2048,2560): uv dot-products.

__global__ void prep_kernel(const float* __restrict__ W1, const float* __restrict__ W2,
                            const float* __restrict__ Wp1,
                            const float* __restrict__ a_src1, const float* __restrict__ a_dst1,
                            const float* __restrict__ a_src2, const float* __restrict__ a_dst2,
                            unsigned short* __restrict__ WT, unsigned short* __restrict__ Wp1T,
                            float* __restrict__ uv){
  __shared__ float tile[32][33];
  int b = blockIdx.x;
  int tx = threadIdx.x & 31, ty = threadIdx.x >> 5;
  if (b < 1024){
    const float* in = (b >> 9) ? W2 : W1;
    int rowOff = (b >> 9) * OUT_C;
    int bb = b & 511;
    int c0 = (bb & 31) * 32, r0 = (bb >> 5) * 32;
    for (int i = ty; i < 32; i += 8)
      tile[i][tx] = in[(size_t)(r0 + i) * OUT_C + c0 + tx];
    __syncthreads();
    for (int i = ty; i < 32; i += 8)
      WT[(size_t)(c0 + i + rowOff) * IN_C + r0 + tx] = f2b(tile[tx][i]);
  } else if (b < 2048){
    int bb = b - 1024;
    int c0 = (bb & 31) * 32, r0 = (bb >> 5) * 32;
    for (int i = ty; i < 32; i += 8)
      tile[i][tx] = Wp1[(size_t)(r0 + i) * OUT_C + c0 + tx];
    __syncthreads();
    for (int i = ty; i < 32; i += 8)
      Wp1T[(size_t)(c0 + i) * OUT_C + r0 + tx] = f2b(tile[tx][i]);
  } else {
    int g = (b - 2048) * 4 + (threadIdx.x >> 6);
    int lane = threadIdx.x & 63;
    int which = g >> 9;
    int i = g & 511;
    const float* W = (which < 2) ? W1 : W2;
    const float* a = (which == 0) ? a_src1 : (which == 1) ? a_dst1 : (which == 2) ? a_src2 : a_dst2;
    const float* row = W + (size_t)i * OUT_C;
    float s = 0.f;
    for (int j = lane; j < OUT_C; j += 64) s += row[j] * a[j];
    for (int off = 32; off; off >>= 1) s += __shfl_down(s, off);
    if (lane == 0) uv[which * IN_C + i] = s;
  }
}

// ---------------- alpha + selfinit + x->bf16 + zero-init ----------------

__global__ void alpha_kernel(const float* __restrict__ x, const float* __restrict__ uv,
                             unsigned short* __restrict__ xb,
                             float* __restrict__ as1, float* __restrict__ ad1,
                             float* __restrict__ as2, float* __restrict__ ad2,
                             float* __restrict__ self1, float* __restrict__ self2,
                             unsigned* __restrict__ m1e, unsigned* __restrict__ m2e,
                             int* counts, int* cursor, float* colsum, float* wv){
  int n = blockIdx.x;
  int w = threadIdx.x >> 6, lane = threadIdx.x & 63;
  __shared__ float sh[4];
  if (threadIdx.x == 0){ counts[n] = 0; cursor[n] = 0; }
  if (n < 8){
    int i = n * 256 + threadIdx.x;
    if (i < 1024) colsum[i] = 0.f; else wv[i - 1024] = 0.f;
  }
  const float* row = x + (size_t)n * IN_C;
  const float* u = uv + w * IN_C;
  float s = 0.f;
  for (int j = lane; j < IN_C; j += 64){
    float v = row[j];
    s += v * u[j];
    if (w == 0) xb[(size_t)n * IN_C + j] = f2b(v);
  }
  for (int off = 32; off; off >>= 1) s += __shfl_down(s, off);
  if (lane == 0){
    sh[w] = s;
    if (w == 0) as1[n] = s;
    else if (w == 1) ad1[n] = s;
    else if (w == 2) as2[n] = s;
    else ad2[n] = s;
  }
  __syncthreads();
  if (threadIdx.x == 0){
    float e1 = leaky(sh[0] + sh[1]);
    float e2 = leaky(sh[2] + sh[3]);
    self1[n] = e1; self2[n] = e2;
    m1e[n] = encf(e1); m2e[n] = encf(e2);
  }
}

// ---------------- CSR build + edge softmax ----------------

__global__ void histmax_kernel(const int* __restrict__ src, const int* __restrict__ dst,
                               const float* __restrict__ as1, const float* __restrict__ ad1,
                               const float* __restrict__ as2, const float* __restrict__ ad2,
                               int* counts, unsigned* m1e, unsigned* m2e, int E){
  int e = blockIdx.x * 256 + threadIdx.x;
  if (e >= E) return;
  int s = src[e], d = dst[e];
  atomicAdd(&counts[d], 1);
  atomicMax(&m1e[d], encf(leaky(as1[s] + ad1[d])));
  atomicMax(&m2e[d], encf(leaky(as2[s] + ad2[d])));
}

__global__ void scan_kernel(const int* __restrict__ counts, int* __restrict__ offs, int n){
  __shared__ int wsum[4];
  int tid = threadIdx.x;
  int wave = tid >> 6, lane = tid & 63;
  int carry = 0;
  for (int base = 0; base < n; base += 256){
    int i = base + tid;
    int v = (i < n) ? counts[i] : 0;
    int sc = v;
    for (int o = 1; o < 64; o <<= 1){
      int t = __shfl_up(sc, o);
      if (lane >= o) sc += t;
    }
    if (lane == 63) wsum[wave] = sc;
    __syncthreads();
    int wp = 0, tot = 0;
#pragma unroll
    for (int k = 0; k < 4; k++){
      int ws = wsum[k];
      if (k < wave) wp += ws;
      tot += ws;
    }
    if (i < n) offs[i] = carry + wp + sc - v;
    carry += tot;
    __syncthreads();
  }
}

__global__ void denominit_kernel(const unsigned* __restrict__ m1e, const unsigned* __restrict__ m2e,
                                 const float* __restrict__ self1, const float* __restrict__ self2,
                                 float* __restrict__ m1, float* __restrict__ m2,
                                 float* __restrict__ den1, float* __restrict__ den2, int N){
  int i = blockIdx.x * 256 + threadIdx.x;
  if (i >= N) return;
  float a = decf(m1e[i]), b = decf(m2e[i]);
  m1[i] = a; m2[i] = b;
  den1[i] = expf(self1[i] - a);
  den2[i] = expf(self2[i] - b);
}

__global__ void scatterexp_kernel(const int* __restrict__ src, const int* __restrict__ dst,
                                  const int* __restrict__ offs, int* cursor,
                                  const float* __restrict__ as1, const float* __restrict__ ad1,
                                  const float* __restrict__ as2, const float* __restrict__ ad2,
                                  const float* __restrict__ m1, const float* __restrict__ m2,
                                  int* __restrict__ nsrc, float* __restrict__ nw1, float* __restrict__ nw2,
                                  float* den1, float* den2, int E){
  int e = blockIdx.x * 256 + threadIdx.x;
  if (e >= E) return;
  int s = src[e], d = dst[e];
  int p = atomicAdd(&cursor[d], 1);
  int idx = offs[d] + p;
  float x1 = expf(leaky(as1[s] + ad1[d]) - m1[d]);
  float x2 = expf(leaky(as2[s] + ad2[d]) - m2[d]);
  nsrc[idx] = s; nw1[idx] = x1; nw2[idx] = x2;
  atomicAdd(&den1[d], x1);
  atomicAdd(&den2[d], x2);
}

// ---------------- aggregate-first ----------------

#define AGG_FMA8(ACC, W, U) \
  ACC[0] += (W) * __uint_as_float(((unsigned)(U).x) << 16); \
  ACC[1] += (W) * __uint_as_float(((unsigned)(U).x) & 0xffff0000u); \
  ACC[2] += (W) * __uint_as_float(((unsigned)(U).y) << 16); \
  ACC[3] += (W) * __uint_as_float(((unsigned)(U).y) & 0xffff0000u); \
  ACC[4] += (W) * __uint_as_float(((unsigned)(U).z) << 16); \
  ACC[5] += (W) * __uint_as_float(((unsigned)(U).z) & 0xffff0000u); \
  ACC[6] += (W) * __uint_as_float(((unsigned)(U).w) << 16); \
  ACC[7] += (W) * __uint_as_float(((unsigned)(U).w) & 0xffff0000u);

__global__ __launch_bounds__(256) void aggx_kernel(
    const int* __restrict__ counts, const int* __restrict__ offs,
    const int* __restrict__ nsrc, const float* __restrict__ nw1, const float* __restrict__ nw2,
    const float* __restrict__ den1, const float* __restrict__ den2,
    const float* __restrict__ self1, const float* __restrict__ self2,
    const float* __restrict__ m1, const float* __restrict__ m2,
    const unsigned short* __restrict__ xb,
    unsigned short* __restrict__ xa1b, unsigned short* __restrict__ xa2b, int N){
  int tid = threadIdx.x;
  int g = tid >> 4, hl = tid & 15;
  int grpbase = tid & 48;
  int d = blockIdx.y * 16 + g;
  if (d >= N) return;
  int colbase = blockIdx.x * 128 + hl * 8;
  float inv1 = 1.f / den1[d], inv2 = 1.f / den2[d];
  int deg = counts[d], off = offs[d];
  float acc1[8] = {0,0,0,0,0,0,0,0}, acc2[8] = {0,0,0,0,0,0,0,0};
  const unsigned short* Xb = xb + colbase;
  for (int base = 0; base < deg; base += 16){
    int i = base + hl;
    int s = 0; float w1 = 0.f, w2 = 0.f;
    if (i < deg){
      int p = off + i;
      s = nsrc[p];
      w1 = nw1[p] * inv1;
      w2 = nw2[p] * inv2;
    }
    int cnt = min(16, deg - base);
#pragma unroll 4
    for (int j = 0; j < cnt; j++){
      int sj = __shfl(s, grpbase + j);
      float w1j = __shfl(w1, grpbase + j);
      float w2j = __shfl(w2, grpbase + j);
      int4 u = *(const int4*)(Xb + (size_t)sj * IN_C);
      AGG_FMA8(acc1, w1j, u)
      AGG_FMA8(acc2, w2j, u)
    }
  }
  {
    float ws1 = expf(self1[d] - m1[d]) * inv1;
    float ws2 = expf(self2[d] - m2[d]) * inv2;
    int4 u = *(const int4*)(Xb + (size_t)d * IN_C);
    AGG_FMA8(acc1, ws1, u)
    AGG_FMA8(acc2, ws2, u)
  }
  size_t outb = (size_t)d * IN_C + colbase;
  int4 o1, o2;
  o1.x = (int)((unsigned)f2b(acc1[0]) | ((unsigned)f2b(acc1[1]) << 16));
  o1.y = (int)((unsigned)f2b(acc1[2]) | ((unsigned)f2b(acc1[3]) << 16));
  o1.z = (int)((unsigned)f2b(acc1[4]) | ((unsigned)f2b(acc1[5]) << 16));
  o1.w = (int)((unsigned)f2b(acc1[6]) | ((unsigned)f2b(acc1[7]) << 16));
  o2.x = (int)((unsigned)f2b(acc2[0]) | ((unsigned)f2b(acc2[1]) << 16));
  o2.y = (int)((unsigned)f2b(acc2[2]) | ((unsigned)f2b(acc2[3]) << 16));
  o2.z = (int)((unsigned)f2b(acc2[4]) | ((unsigned)f2b(acc2[5]) << 16));
  o2.w = (int)((unsigned)f2b(acc2[6]) | ((unsigned)f2b(acc2[7]) << 16));
  *(int4*)(xa1b + outb) = o1;
  *(int4*)(xa2b + outb) = o2;
}

// ---------------- fused GEMM-H, interleaved K-loop ----------------
// 16 iterations; per iteration: stage A1/B1/A2/B2 (32 KB LDS), 1 barrier, 32 MFMA, 1 barrier.

__global__ __launch_bounds__(256) void gemmh_kernel(const unsigned short* __restrict__ A1,
                                                    const unsigned short* __restrict__ A2,
                                                    const unsigned short* __restrict__ BT,
                                                    const float* __restrict__ b1,
                                                    const float* __restrict__ b2,
                                                    const float* __restrict__ prelu_a,
                                                    unsigned short* __restrict__ hsum,
                                                    unsigned short* __restrict__ hdiff,
                                                    int M, int Mtiles, int perx){
  const int bid = blockIdx.x;
  const int xcd = bid & 7;
  const int li = bid >> 3;
  const int bn_t = li & 7;
  const int bm_t = xcd * perx + (li >> 3);
  if (bm_t >= Mtiles) return;
  const int bm = bm_t * 128, bn = bn_t * 128;
  __shared__ unsigned short Al1[128 * 32];
  __shared__ unsigned short Bl1[128 * 32];
  __shared__ unsigned short Al2[128 * 32];
  __shared__ unsigned short Bl2[128 * 32];
  const int t = threadIdx.x;
  const int lane = t & 63, wid = t >> 6;
  const int wi = wid & 1, wj = wid >> 1;
  const int l16 = lane & 15, q = lane >> 4;
  const int lrow = lane >> 2;
  const int lch = (lane & 3) * 8;
  f32x4 acc1[4][4] = {};
  f32x4 acc2[4][4] = {};
  const int r0 = wid * 32 + lrow;
  const int r1 = r0 + 16;
  const int ga0 = min(bm + r0, M - 1);
  const int ga1 = min(bm + r1, M - 1);
  const unsigned short* pa1_0 = A1 + (size_t)ga0 * IN_C + lch;
  const unsigned short* pa1_1 = A1 + (size_t)ga1 * IN_C + lch;
  const unsigned short* pa2_0 = A2 + (size_t)ga0 * IN_C + lch;
  const unsigned short* pa2_1 = A2 + (size_t)ga1 * IN_C + lch;
  const unsigned short* pb1_0 = BT + (size_t)(bn + r0) * IN_C + lch;
  const unsigned short* pb1_1 = BT + (size_t)(bn + r1) * IN_C + lch;
  const unsigned short* pb2_0 = BT + (size_t)(OUT_C + bn + r0) * IN_C + lch;
  const unsigned short* pb2_1 = BT + (size_t)(OUT_C + bn + r1) * IN_C + lch;
  for (int k0 = 0; k0 < IN_C; k0 += 32){
    GLOAD_LDS16(pa1_0 + k0, &Al1[(wid * 32) * 32]);
    GLOAD_LDS16(pa1_1 + k0, &Al1[(wid * 32 + 16) * 32]);
    GLOAD_LDS16(pb1_0 + k0, &Bl1[(wid * 32) * 32]);
    GLOAD_LDS16(pb1_1 + k0, &Bl1[(wid * 32 + 16) * 32]);
    GLOAD_LDS16(pa2_0 + k0, &Al2[(wid * 32) * 32]);
    GLOAD_LDS16(pa2_1 + k0, &Al2[(wid * 32 + 16) * 32]);
    GLOAD_LDS16(pb2_0 + k0, &Bl2[(wid * 32) * 32]);
    GLOAD_LDS16(pb2_1 + k0, &Bl2[(wid * 32 + 16) * 32]);
    __syncthreads();
    {
      frag8 af[4], bf[4];
#pragma unroll
      for (int mi = 0; mi < 4; mi++) af[mi] = *(const frag8*)&Al1[(wi*64 + mi*16 + l16) * 32 + q*8];
#pragma unroll
      for (int nj = 0; nj < 4; nj++) bf[nj] = *(const frag8*)&Bl1[(wj*64 + nj*16 + l16) * 32 + q*8];
#pragma unroll
      for (int mi = 0; mi < 4; mi++)
#pragma unroll
        for (int nj = 0; nj < 4; nj++)
          acc1[mi][nj] = __builtin_amdgcn_mfma_f32_16x16x32_bf16(af[mi], bf[nj], acc1[mi][nj], 0, 0, 0);
    }
    {
      frag8 af[4], bf[4];
#pragma unroll
      for (int mi = 0; mi < 4; mi++) af[mi] = *(const frag8*)&Al2[(wi*64 + mi*16 + l16) * 32 + q*8];
#pragma unroll
      for (int nj = 0; nj < 4; nj++) bf[nj] = *(const frag8*)&Bl2[(wj*64 + nj*16 + l16) * 32 + q*8];
#pragma unroll
      for (int mi = 0; mi < 4; mi++)
#pragma unroll
        for (int nj = 0; nj < 4; nj++)
          acc2[mi][nj] = __builtin_amdgcn_mfma_f32_16x16x32_bf16(af[mi], bf[nj], acc2[mi][nj], 0, 0, 0);
    }
    __syncthreads();
  }
  float pa = prelu_a[0];
#pragma unroll
  for (int mi = 0; mi < 4; mi++){
#pragma unroll
    for (int r = 0; r < 4; r++){
      int row = bm + wi*64 + mi*16 + q*4 + r;
      if (row >= M) continue;
#pragma unroll
      for (int nj = 0; nj < 4; nj++){
        int col = bn + wj*64 + nj*16 + l16;
        float v1 = acc1[mi][nj][r] + b1[col];
        v1 = v1 >= 0.f ? v1 : pa * v1;
        float v2 = acc2[mi][nj][r] + b2[col];
        v2 = v2 >= 0.f ? v2 : pa * v2;
        size_t idx = (size_t)row * OUT_C + col;
        hsum[idx]  = f2b(v1 + v2);
        hdiff[idx] = f2b(v1 - v2);
      }
    }
  }
}

// ---------------- GEMM2: colsum += sum_rows tanh(hsum @ Wp1 + bp1), BK=64 ----------------

__global__ __launch_bounds__(256) void gemm2_kernel(const unsigned short* __restrict__ A,
                                                    const unsigned short* __restrict__ BT,
                                                    const float* __restrict__ bp1,
                                                    float* __restrict__ colsum,
                                                    int M, int Mtiles, int perx){
  const int bid = blockIdx.x;
  const int xcd = bid & 7;
  const int li = bid >> 3;
  const int bn_t = li & 7;
  const int bm_t = xcd * perx + (li >> 3);
  if (bm_t >= Mtiles) return;
  const int bm = bm_t * 128, bn = bn_t * 128;
  __shared__ unsigned short Al[2][128 * 32];
  __shared__ unsigned short Bl[2][128 * 32];
  __shared__ float cs[128];
  const int t = threadIdx.x;
  const int lane = t & 63, wid = t >> 6;
  const int wi = wid & 1, wj = wid >> 1;
  const int l16 = lane & 15, q = lane >> 4;
  const int lrow = lane >> 2;
  const int lch = (lane & 3) * 8;
  if (t < 128) cs[t] = 0.f;
  f32x4 acc[4][4] = {};
  const int r0 = wid * 32 + lrow;
  const int r1 = r0 + 16;
  const int ga0 = min(bm + r0, M - 1);
  const int ga1 = min(bm + r1, M - 1);
  const unsigned short* pa0 = A + (size_t)ga0 * OUT_C + lch;
  const unsigned short* pa1 = A + (size_t)ga1 * OUT_C + lch;
  const unsigned short* pb0 = BT + (size_t)(bn + r0) * OUT_C + lch;
  const unsigned short* pb1 = BT + (size_t)(bn + r1) * OUT_C + lch;
  for (int k0 = 0; k0 < OUT_C; k0 += 64){
    GLOAD_LDS16(pa0 + k0, &Al[0][(wid * 32) * 32]);
    GLOAD_LDS16(pa1 + k0, &Al[0][(wid * 32 + 16) * 32]);
    GLOAD_LDS16(pb0 + k0, &Bl[0][(wid * 32) * 32]);
    GLOAD_LDS16(pb1 + k0, &Bl[0][(wid * 32 + 16) * 32]);
    GLOAD_LDS16(pa0 + k0 + 32, &Al[1][(wid * 32) * 32]);
    GLOAD_LDS16(pa1 + k0 + 32, &Al[1][(wid * 32 + 16) * 32]);
    GLOAD_LDS16(pb0 + k0 + 32, &Bl[1][(wid * 32) * 32]);
    GLOAD_LDS16(pb1 + k0 + 32, &Bl[1][(wid * 32 + 16) * 32]);
    __syncthreads();
#pragma unroll
    for (int sub = 0; sub < 2; sub++){
      frag8 af[4], bf[4];
#pragma unroll
      for (int mi = 0; mi < 4; mi++) af[mi] = *(const frag8*)&Al[sub][(wi*64 + mi*16 + l16) * 32 + q*8];
#pragma unroll
      for (int nj = 0; nj < 4; nj++) bf[nj] = *(const frag8*)&Bl[sub][(wj*64 + nj*16 + l16) * 32 + q*8];
#pragma unroll
      for (int mi = 0; mi < 4; mi++)
#pragma unroll
        for (int nj = 0; nj < 4; nj++)
          acc[mi][nj] = __builtin_amdgcn_mfma_f32_16x16x32_bf16(af[mi], bf[nj], acc[mi][nj], 0, 0, 0);
    }
    __syncthreads();
  }
#pragma unroll
  for (int nj = 0; nj < 4; nj++){
    int col = bn + wj*64 + nj*16 + l16;
    float bias = bp1[col];
    float p = 0.f;
#pragma unroll
    for (int mi = 0; mi < 4; mi++){
#pragma unroll
      for (int r = 0; r < 4; r++){
        int row = bm + wi*64 + mi*16 + q*4 + r;
        float tv = tanhf(acc[mi][nj][r] + bias);
        if (row < M) p += tv;
      }
    }
    p += __shfl_xor(p, 16);
    p += __shfl_xor(p, 32);
    if (q == 0) atomicAdd(&cs[wj*64 + nj*16 + l16], p);
  }
  __syncthreads();
  if (t < 128) atomicAdd(&colsum[bn + t], cs[t]);
}

// ---------------- semantic attention tail ----------------

__global__ void wproj_kernel(const float* __restrict__ colsum, const float* __restrict__ Wp2,
                             float* __restrict__ wv){
  int o = blockIdx.x * 256 + threadIdx.x;
  int c0 = blockIdx.y * 128;
  float acc = 0.f;
  for (int c = c0; c < c0 + 128; c++) acc += colsum[c] * Wp2[(size_t)c * OUT_C + o];
  atomicAdd(&wv[o], acc);
}

__global__ __launch_bounds__(1024) void softmax_kernel(const float* __restrict__ wv,
                                                       float* __restrict__ att, float invN){
  int o = threadIdx.x;
  __shared__ float red[1024];
  float w = wv[o] * invN;
  red[o] = w; __syncthreads();
  for (int s = 512; s > 0; s >>= 1){ if (o < s) red[o] = fmaxf(red[o], red[o + s]); __syncthreads(); }
  float m = red[0]; __syncthreads();
  float e = expf(w - m);
  red[o] = e; __syncthreads();
  for (int s = 512; s > 0; s >>= 1){ if (o < s) red[o] += red[o + s]; __syncthreads(); }
  att[o] = e / red[0];
}

// out = 0.5*s + (att-0.5)*d
__global__ void combine_kernel(const float* __restrict__ att, const unsigned short* __restrict__ hs,
                               const unsigned short* __restrict__ hd, float* __restrict__ out, int total8){
  int i = blockIdx.x * 256 + threadIdx.x;
  if (i >= total8) return;
  int colb = (i & 127) * 8;
  int4 us = ((const int4*)hs)[i];
  int4 ud = ((const int4*)hd)[i];
  float4 a0 = *(const float4*)(att + colb);
  float4 a1 = *(const float4*)(att + colb + 4);
  float o[8]; float sv, dv;
  sv = __uint_as_float(((unsigned)us.x) << 16);        dv = __uint_as_float(((unsigned)ud.x) << 16);
  o[0] = 0.5f * sv + (a0.x - 0.5f) * dv;
  sv = __uint_as_float(((unsigned)us.x) & 0xffff0000u); dv = __uint_as_float(((unsigned)ud.x) & 0xffff0000u);
  o[1] = 0.5f * sv + (a0.y - 0.5f) * dv;
  sv = __uint_as_float(((unsigned)us.y) << 16);        dv = __uint_as_float(((unsigned)ud.y) << 16);
  o[2] = 0.5f * sv + (a0.z - 0.5f) * dv;
  sv = __uint_as_float(((unsigned)us.y) & 0xffff0000u); dv = __uint_as_float(((unsigned)ud.y) & 0xffff0000u);
  o[3] = 0.5f * sv + (a0.w - 0.5f) * dv;
  sv = __uint_as_float(((unsigned)us.z) << 16);        dv = __uint_as_float(((unsigned)ud.z) << 16);
  o[4] = 0.5f * sv + (a1.x - 0.5f) * dv;
  sv = __uint_as_float(((unsigned)us.z) & 0xffff0000u); dv = __uint_as_float(((unsigned)ud.z) & 0xffff0000u);
  o[5] = 0.5f * sv + (a1.y - 0.5f) * dv;
  sv = __uint_as_float(((unsigned)us.w) << 16);        dv = __uint_as_float(((unsigned)ud.w) << 16);
  o[6] = 0.5f * sv + (a1.z - 0.5f) * dv;
  sv = __uint_as_float(((unsigned)us.w) & 0xffff0000u); dv = __uint_as_float(((unsigned)ud.w) & 0xffff0000u);
  o[7] = 0.5f * sv + (a1.w - 0.5f) * dv;
  float4 f0; f0.x = o[0]; f0.y = o[1]; f0.z = o[2]; f0.w = o[3];
  float4 f1; f1.x = o[4]; f1.y = o[5]; f1.z = o[6]; f1.w = o[7];
  *(float4*)(out + (size_t)i * 8) = f0;
  *(float4*)(out + (size_t)i * 8 + 4) = f1;
}

// ---------------- launch ----------------

extern "C" void kernel_launch(void* const* d_in, const int* in_sizes, int n_in,
                              void* d_out, int out_size, void* d_ws, size_t ws_size,
                              hipStream_t stream){
  const float* x      = (const float*)d_in[0];
  const int*   edge   = (const int*)d_in[1];
  const float* W1     = (const float*)d_in[2];
  const float* a_src1 = (const float*)d_in[3];
  const float* a_dst1 = (const float*)d_in[4];
  const float* b1     = (const float*)d_in[5];
  const float* W2     = (const float*)d_in[6];
  const float* a_src2 = (const float*)d_in[7];
  const float* a_dst2 = (const float*)d_in[8];
  const float* b2     = (const float*)d_in[9];
  const float* prelu_a= (const float*)d_in[10];
  const float* Wp1    = (const float*)d_in[11];
  const float* bp1    = (const float*)d_in[12];
  const float* Wp2    = (const float*)d_in[13];
  const int N = in_sizes[0] / IN_C;
  const int E = in_sizes[1] / 2;
  const int* srcArr = edge;
  const int* dstArr = edge + E;

  char* ws = (char*)d_ws;
  size_t o = 0;
  auto alloc = [&](size_t b) -> char* {
    char* p = ws + o;
    o = (o + b + 255) & ~(size_t)255;
    return p;
  };
  unsigned short* xb    = (unsigned short*)alloc((size_t)N * IN_C * 2);
  unsigned short* WT    = (unsigned short*)alloc((size_t)NC2 * IN_C * 2);
  unsigned short* Wp1T  = (unsigned short*)alloc((size_t)OUT_C * OUT_C * 2);
  unsigned short* xa1b  = (unsigned short*)alloc((size_t)N * IN_C * 2);
  unsigned short* xa2b  = (unsigned short*)alloc((size_t)N * IN_C * 2);
  unsigned short* hsum  = (unsigned short*)alloc((size_t)N * OUT_C * 2);
  unsigned short* hdiff = (unsigned short*)alloc((size_t)N * OUT_C * 2);
  float*          uv    = (float*)alloc(4 * IN_C * 4);
  float*          as1   = (float*)alloc((size_t)4 * N * 4);
  float* ad1 = as1 + N; float* as2 = as1 + 2 * N; float* ad2 = as1 + 3 * N;
  float*          self1 = (float*)alloc((size_t)2 * N * 4); float* self2 = self1 + N;
  unsigned*       m1e   = (unsigned*)alloc((size_t)2 * N * 4); unsigned* m2e = m1e + N;
  float*          m1    = (float*)alloc((size_t)2 * N * 4); float* m2 = m1 + N;
  float*          den1  = (float*)alloc((size_t)2 * N * 4); float* den2 = den1 + N;
  int*            counts= (int*)alloc((size_t)N * 4);
  int*            offs  = (int*)alloc((size_t)(N + 1) * 4);
  int*            cursor= (int*)alloc((size_t)N * 4);
  int*            nsrc  = (int*)alloc((size_t)E * 4);
  float*          nw1   = (float*)alloc((size_t)E * 4);
  float*          nw2   = (float*)alloc((size_t)E * 4);
  float*          colsum= (float*)alloc(OUT_C * 4);
  float*          wv    = (float*)alloc(OUT_C * 4);
  float*          att   = (float*)alloc(OUT_C * 4);

  const int Mtiles = (N + 127) / 128;
  const int perx = (Mtiles + 7) / 8;
  const int gemmgrid = 8 * perx * 8;

  prep_kernel<<<2560, 256, 0, stream>>>(W1, W2, Wp1, a_src1, a_dst1, a_src2, a_dst2, WT, Wp1T, uv);
  alpha_kernel<<<N, 256, 0, stream>>>(x, uv, xb, as1, ad1, as2, ad2, self1, self2, m1e, m2e,
                                      counts, cursor, colsum, wv);
  histmax_kernel<<<(E + 255) / 256, 256, 0, stream>>>(srcArr, dstArr, as1, ad1, as2, ad2,
                                                      counts, m1e, m2e, E);
  scan_kernel<<<1, 256, 0, stream>>>(counts, offs, N);
  denominit_kernel<<<(N + 255) / 256, 256, 0, stream>>>(m1e, m2e, self1, self2, m1, m2, den1, den2, N);
  scatterexp_kernel<<<(E + 255) / 256, 256, 0, stream>>>(srcArr, dstArr, offs, cursor,
                                                         as1, ad1, as2, ad2, m1, m2,
                                                         nsrc, nw1, nw2, den1, den2, E);
  aggx_kernel<<<dim3(4, (N + 15) / 16), 256, 0, stream>>>(counts, offs, nsrc, nw1, nw2, den1, den2,
                                                          self1, self2, m1, m2, xb, xa1b, xa2b, N);
  gemmh_kernel<<<gemmgrid, 256, 0, stream>>>(xa1b, xa2b, WT, b1, b2, prelu_a,
                                             hsum, hdiff, N, Mtiles, perx);
  gemm2_kernel<<<gemmgrid, 256, 0, stream>>>(hsum, Wp1T, bp1, colsum, N, Mtiles, perx);
  wproj_kernel<<<dim3(4, 8), 256, 0, stream>>>(colsum, Wp2, wv);
  softmax_kernel<<<1, 1024, 0, stream>>>(wv, att, 1.0f / (float)N);
  combine_kernel<<<(N * OUT_C / 8 + 255) / 256, 256, 0, stream>>>(att, hsum, hdiff, (float*)d_out,
                                                                  N * OUT_C / 8);
}

// Round 8
// 328.325 us; speedup vs baseline: 1.1676x; 1.1676x over previous
//
#include <hip/hip_runtime.h>

#define IN_C 512
#define OUT_C 1024
#define NC2 2048
#define NEG_SLOPE 0.2f

typedef short frag8 __attribute__((ext_vector_type(8)));
typedef float f32x4 __attribute__((ext_vector_type(4)));

#define GLOAD_LDS16(g, l) __builtin_amdgcn_global_load_lds(\
    (const __attribute__((address_space(1))) void*)(g), \
    (__attribute__((address_space(3))) void*)(l), 16, 0, 0)

__device__ __forceinline__ unsigned short f2b(float f){
  unsigned u = __float_as_uint(f);
  unsigned r = (u + 0x7fffu + ((u >> 16) & 1u)) >> 16;
  return (unsigned short)r;
}
__device__ __forceinline__ unsigned encf(float f){
  unsigned u = __float_as_uint(f);
  return (u & 0x80000000u) ? ~u : (u | 0x80000000u);
}
__device__ __forceinline__ float decf(unsigned u){
  unsigned v = (u & 0x80000000u) ? (u & 0x7fffffffu) : ~u;
  return __uint_as_float(v);
}
__device__ __forceinline__ float leaky(float v){ return v >= 0.f ? v : NEG_SLOPE * v; }

// ---------------- fused preprocessing ----------------

__global__ void prep_kernel(const float* __restrict__ W1, const float* __restrict__ W2,
                            const float* __restrict__ Wp1,
                            const float* __restrict__ a_src1, const float* __restrict__ a_dst1,
                            const float* __restrict__ a_src2, const float* __restrict__ a_dst2,
                            unsigned short* __restrict__ WT, unsigned short* __restrict__ Wp1T,
                            float* __restrict__ uv){
  __shared__ float tile[32][33];
  int b = blockIdx.x;
  int tx = threadIdx.x & 31, ty = threadIdx.x >> 5;
  if (b < 1024){
    const float* in = (b >> 9) ? W2 : W1;
    int rowOff = (b >> 9) * OUT_C;
    int bb = b & 511;
    int c0 = (bb & 31) * 32, r0 = (bb >> 5) * 32;
    for (int i = ty; i < 32; i += 8)
      tile[i][tx] = in[(size_t)(r0 + i) * OUT_C + c0 + tx];
    __syncthreads();
    for (int i = ty; i < 32; i += 8)
      WT[(size_t)(c0 + i + rowOff) * IN_C + r0 + tx] = f2b(tile[tx][i]);
  } else if (b < 2048){
    int bb = b - 1024;
    int c0 = (bb & 31) * 32, r0 = (bb >> 5) * 32;
    for (int i = ty; i < 32; i += 8)
      tile[i][tx] = Wp1[(size_t)(r0 + i) * OUT_C + c0 + tx];
    __syncthreads();
    for (int i = ty; i < 32; i += 8)
      Wp1T[(size_t)(c0 + i) * OUT_C + r0 + tx] = f2b(tile[tx][i]);
  } else {
    int g = (b - 2048) * 4 + (threadIdx.x >> 6);
    int lane = threadIdx.x & 63;
    int which = g >> 9;
    int i = g & 511;
    const float* W = (which < 2) ? W1 : W2;
    const float* a = (which == 0) ? a_src1 : (which == 1) ? a_dst1 : (which == 2) ? a_src2 : a_dst2;
    const float* row = W + (size_t)i * OUT_C;
    float s = 0.f;
    for (int j = lane; j < OUT_C; j += 64) s += row[j] * a[j];
    for (int off = 32; off; off >>= 1) s += __shfl_down(s, off);
    if (lane == 0) uv[which * IN_C + i] = s;
  }
}

// ---------------- alpha + selfinit + x->bf16 + zero-init ----------------

__global__ void alpha_kernel(const float* __restrict__ x, const float* __restrict__ uv,
                             unsigned short* __restrict__ xb,
                             float* __restrict__ as1, float* __restrict__ ad1,
                             float* __restrict__ as2, float* __restrict__ ad2,
                             float* __restrict__ self1, float* __restrict__ self2,
                             unsigned* __restrict__ m1e, unsigned* __restrict__ m2e,
                             int* counts, int* cursor, float* colsum, float* wv){
  int n = blockIdx.x;
  int w = threadIdx.x >> 6, lane = threadIdx.x & 63;
  __shared__ float sh[4];
  if (threadIdx.x == 0){ counts[n] = 0; cursor[n] = 0; }
  if (n < 8){
    int i = n * 256 + threadIdx.x;
    if (i < 1024) colsum[i] = 0.f; else wv[i - 1024] = 0.f;
  }
  const float* row = x + (size_t)n * IN_C;
  const float* u = uv + w * IN_C;
  float s = 0.f;
  for (int j = lane; j < IN_C; j += 64){
    float v = row[j];
    s += v * u[j];
    if (w == 0) xb[(size_t)n * IN_C + j] = f2b(v);
  }
  for (int off = 32; off; off >>= 1) s += __shfl_down(s, off);
  if (lane == 0){
    sh[w] = s;
    if (w == 0) as1[n] = s;
    else if (w == 1) ad1[n] = s;
    else if (w == 2) as2[n] = s;
    else ad2[n] = s;
  }
  __syncthreads();
  if (threadIdx.x == 0){
    float e1 = leaky(sh[0] + sh[1]);
    float e2 = leaky(sh[2] + sh[3]);
    self1[n] = e1; self2[n] = e2;
    m1e[n] = encf(e1); m2e[n] = encf(e2);
  }
}

// ---------------- CSR build + edge softmax ----------------

__global__ void histmax_kernel(const int* __restrict__ src, const int* __restrict__ dst,
                               const float* __restrict__ as1, const float* __restrict__ ad1,
                               const float* __restrict__ as2, const float* __restrict__ ad2,
                               int* counts, unsigned* m1e, unsigned* m2e, int E){
  int e = blockIdx.x * 256 + threadIdx.x;
  if (e >= E) return;
  int s = src[e], d = dst[e];
  atomicAdd(&counts[d], 1);
  atomicMax(&m1e[d], encf(leaky(as1[s] + ad1[d])));
  atomicMax(&m2e[d], encf(leaky(as2[s] + ad2[d])));
}

// 3-phase parallel scan: local (exclusive within 256-chunk) + chunk sums
__global__ void scanA_kernel(const int* __restrict__ counts, int* __restrict__ offs,
                             int* __restrict__ bsum, int n){
  __shared__ int wsum[4];
  int i = blockIdx.x * 256 + threadIdx.x;
  int wave = threadIdx.x >> 6, lane = threadIdx.x & 63;
  int v = (i < n) ? counts[i] : 0;
  int sc = v;
  for (int o = 1; o < 64; o <<= 1){
    int t = __shfl_up(sc, o);
    if (lane >= o) sc += t;
  }
  if (lane == 63) wsum[wave] = sc;
  __syncthreads();
  int wp = 0, tot = 0;
#pragma unroll
  for (int k = 0; k < 4; k++){
    int ws = wsum[k];
    if (k < wave) wp += ws;
    tot += ws;
  }
  if (i < n) offs[i] = wp + sc - v;
  if (threadIdx.x == 0) bsum[blockIdx.x] = tot;
}

// exclusive scan of nb (<=64) chunk sums, single wave
__global__ void scanB_kernel(int* __restrict__ bsum, int nb){
  int lane = threadIdx.x;
  int v = (lane < nb) ? bsum[lane] : 0;
  int sc = v;
  for (int o = 1; o < 64; o <<= 1){
    int t = __shfl_up(sc, o);
    if (lane >= o) sc += t;
  }
  if (lane < nb) bsum[lane] = sc - v;
}

__global__ void scanC_kernel(int* __restrict__ offs, const int* __restrict__ bsum, int n){
  int i = blockIdx.x * 256 + threadIdx.x;
  if (i < n) offs[i] += bsum[blockIdx.x];
}

__global__ void denominit_kernel(const unsigned* __restrict__ m1e, const unsigned* __restrict__ m2e,
                                 const float* __restrict__ self1, const float* __restrict__ self2,
                                 float* __restrict__ m1, float* __restrict__ m2,
                                 float* __restrict__ den1, float* __restrict__ den2, int N){
  int i = blockIdx.x * 256 + threadIdx.x;
  if (i >= N) return;
  float a = decf(m1e[i]), b = decf(m2e[i]);
  m1[i] = a; m2[i] = b;
  den1[i] = expf(self1[i] - a);
  den2[i] = expf(self2[i] - b);
}

__global__ void scatterexp_kernel(const int* __restrict__ src, const int* __restrict__ dst,
                                  const int* __restrict__ offs, int* cursor,
                                  const float* __restrict__ as1, const float* __restrict__ ad1,
                                  const float* __restrict__ as2, const float* __restrict__ ad2,
                                  const float* __restrict__ m1, const float* __restrict__ m2,
                                  int* __restrict__ nsrc, float* __restrict__ nw1, float* __restrict__ nw2,
                                  float* den1, float* den2, int E){
  int e = blockIdx.x * 256 + threadIdx.x;
  if (e >= E) return;
  int s = src[e], d = dst[e];
  int p = atomicAdd(&cursor[d], 1);
  int idx = offs[d] + p;
  float x1 = expf(leaky(as1[s] + ad1[d]) - m1[d]);
  float x2 = expf(leaky(as2[s] + ad2[d]) - m2[d]);
  nsrc[idx] = s; nw1[idx] = x1; nw2[idx] = x2;
  atomicAdd(&den1[d], x1);
  atomicAdd(&den2[d], x2);
}

// ---------------- aggregate-first ----------------

#define AGG_FMA8(ACC, W, U) \
  ACC[0] += (W) * __uint_as_float(((unsigned)(U).x) << 16); \
  ACC[1] += (W) * __uint_as_float(((unsigned)(U).x) & 0xffff0000u); \
  ACC[2] += (W) * __uint_as_float(((unsigned)(U).y) << 16); \
  ACC[3] += (W) * __uint_as_float(((unsigned)(U).y) & 0xffff0000u); \
  ACC[4] += (W) * __uint_as_float(((unsigned)(U).z) << 16); \
  ACC[5] += (W) * __uint_as_float(((unsigned)(U).z) & 0xffff0000u); \
  ACC[6] += (W) * __uint_as_float(((unsigned)(U).w) << 16); \
  ACC[7] += (W) * __uint_as_float(((unsigned)(U).w) & 0xffff0000u);

__global__ __launch_bounds__(256) void aggx_kernel(
    const int* __restrict__ counts, const int* __restrict__ offs,
    const int* __restrict__ nsrc, const float* __restrict__ nw1, const float* __restrict__ nw2,
    const float* __restrict__ den1, const float* __restrict__ den2,
    const float* __restrict__ self1, const float* __restrict__ self2,
    const float* __restrict__ m1, const float* __restrict__ m2,
    const unsigned short* __restrict__ xb,
    unsigned short* __restrict__ xa1b, unsigned short* __restrict__ xa2b, int N){
  int tid = threadIdx.x;
  int g = tid >> 4, hl = tid & 15;
  int grpbase = tid & 48;
  int d = blockIdx.y * 16 + g;
  if (d >= N) return;
  int colbase = blockIdx.x * 128 + hl * 8;
  float inv1 = 1.f / den1[d], inv2 = 1.f / den2[d];
  int deg = counts[d], off = offs[d];
  float acc1[8] = {0,0,0,0,0,0,0,0}, acc2[8] = {0,0,0,0,0,0,0,0};
  const unsigned short* Xb = xb + colbase;
  for (int base = 0; base < deg; base += 16){
    int i = base + hl;
    int s = 0; float w1 = 0.f, w2 = 0.f;
    if (i < deg){
      int p = off + i;
      s = nsrc[p];
      w1 = nw1[p] * inv1;
      w2 = nw2[p] * inv2;
    }
    int cnt = min(16, deg - base);
#pragma unroll 4
    for (int j = 0; j < cnt; j++){
      int sj = __shfl(s, grpbase + j);
      float w1j = __shfl(w1, grpbase + j);
      float w2j = __shfl(w2, grpbase + j);
      int4 u = *(const int4*)(Xb + (size_t)sj * IN_C);
      AGG_FMA8(acc1, w1j, u)
      AGG_FMA8(acc2, w2j, u)
    }
  }
  {
    float ws1 = expf(self1[d] - m1[d]) * inv1;
    float ws2 = expf(self2[d] - m2[d]) * inv2;
    int4 u = *(const int4*)(Xb + (size_t)d * IN_C);
    AGG_FMA8(acc1, ws1, u)
    AGG_FMA8(acc2, ws2, u)
  }
  size_t outb = (size_t)d * IN_C + colbase;
  int4 o1, o2;
  o1.x = (int)((unsigned)f2b(acc1[0]) | ((unsigned)f2b(acc1[1]) << 16));
  o1.y = (int)((unsigned)f2b(acc1[2]) | ((unsigned)f2b(acc1[3]) << 16));
  o1.z = (int)((unsigned)f2b(acc1[4]) | ((unsigned)f2b(acc1[5]) << 16));
  o1.w = (int)((unsigned)f2b(acc1[6]) | ((unsigned)f2b(acc1[7]) << 16));
  o2.x = (int)((unsigned)f2b(acc2[0]) | ((unsigned)f2b(acc2[1]) << 16));
  o2.y = (int)((unsigned)f2b(acc2[2]) | ((unsigned)f2b(acc2[3]) << 16));
  o2.z = (int)((unsigned)f2b(acc2[4]) | ((unsigned)f2b(acc2[5]) << 16));
  o2.w = (int)((unsigned)f2b(acc2[6]) | ((unsigned)f2b(acc2[7]) << 16));
  *(int4*)(xa1b + outb) = o1;
  *(int4*)(xa2b + outb) = o2;
}

// ---------------- fused GEMM-H: 64x128 tiles for 2x grid concurrency ----------------
// Sequential two GEMM loops (R6 structure), 12 KB LDS, acc[4][2] per array.
// 1-D swizzled grid: xcd = bid%8 owns a band of M-tiles; bn cycles fastest.

__global__ __launch_bounds__(256) void gemmh_kernel(const unsigned short* __restrict__ A1,
                                                    const unsigned short* __restrict__ A2,
                                                    const unsigned short* __restrict__ BT,
                                                    const float* __restrict__ b1,
                                                    const float* __restrict__ b2,
                                                    const float* __restrict__ prelu_a,
                                                    unsigned short* __restrict__ hsum,
                                                    unsigned short* __restrict__ hdiff,
                                                    int M, int Mtiles, int perx){
  const int bid = blockIdx.x;
  const int xcd = bid & 7;
  const int li = bid >> 3;
  const int bn_t = li & 7;
  const int bm_t = xcd * perx + (li >> 3);
  if (bm_t >= Mtiles) return;
  const int bm = bm_t * 64, bn = bn_t * 128;
  __shared__ unsigned short Al[64 * 32];   // 4 KB
  __shared__ unsigned short Bl[128 * 32];  // 8 KB
  const int t = threadIdx.x;
  const int lane = t & 63, wid = t >> 6;
  const int wj = wid;                      // wave -> 32-col quarter
  const int l16 = lane & 15, q = lane >> 4;
  const int lch = (lane & 3) * 8;
  f32x4 acc1[4][2] = {};
  f32x4 acc2[4][2] = {};
  const int arow = bm + wid * 16 + (lane >> 2);       // A stage row (1 issue/wave)
  const int brow0 = bn + wid * 32 + (lane >> 2);      // B stage rows (2 issues/wave)
  const int ga = min(arow, M - 1);
  const unsigned short* pa1 = A1 + (size_t)ga * IN_C + lch;
  const unsigned short* pa2 = A2 + (size_t)ga * IN_C + lch;
  const unsigned short* pb0 = BT + (size_t)brow0 * IN_C + lch;
  const unsigned short* pb1 = BT + (size_t)(brow0 + 16) * IN_C + lch;
  const size_t boff2 = (size_t)OUT_C * IN_C;
  // ---- GEMM 1 ----
  for (int k0 = 0; k0 < IN_C; k0 += 32){
    GLOAD_LDS16(pa1 + k0, &Al[(wid * 16) * 32]);
    GLOAD_LDS16(pb0 + k0, &Bl[(wid * 32) * 32]);
    GLOAD_LDS16(pb1 + k0, &Bl[(wid * 32 + 16) * 32]);
    __syncthreads();
    frag8 af[4], bf[2];
#pragma unroll
    for (int mi = 0; mi < 4; mi++) af[mi] = *(const frag8*)&Al[(mi*16 + l16) * 32 + q*8];
#pragma unroll
    for (int nj = 0; nj < 2; nj++) bf[nj] = *(const frag8*)&Bl[(wj*32 + nj*16 + l16) * 32 + q*8];
#pragma unroll
    for (int mi = 0; mi < 4; mi++)
#pragma unroll
      for (int nj = 0; nj < 2; nj++)
        acc1[mi][nj] = __builtin_amdgcn_mfma_f32_16x16x32_bf16(af[mi], bf[nj], acc1[mi][nj], 0, 0, 0);
    __syncthreads();
  }
  // ---- GEMM 2 ----
  for (int k0 = 0; k0 < IN_C; k0 += 32){
    GLOAD_LDS16(pa2 + k0, &Al[(wid * 16) * 32]);
    GLOAD_LDS16(pb0 + boff2 + k0, &Bl[(wid * 32) * 32]);
    GLOAD_LDS16(pb1 + boff2 + k0, &Bl[(wid * 32 + 16) * 32]);
    __syncthreads();
    frag8 af[4], bf[2];
#pragma unroll
    for (int mi = 0; mi < 4; mi++) af[mi] = *(const frag8*)&Al[(mi*16 + l16) * 32 + q*8];
#pragma unroll
    for (int nj = 0; nj < 2; nj++) bf[nj] = *(const frag8*)&Bl[(wj*32 + nj*16 + l16) * 32 + q*8];
#pragma unroll
    for (int mi = 0; mi < 4; mi++)
#pragma unroll
      for (int nj = 0; nj < 2; nj++)
        acc2[mi][nj] = __builtin_amdgcn_mfma_f32_16x16x32_bf16(af[mi], bf[nj], acc2[mi][nj], 0, 0, 0);
    __syncthreads();
  }
  float pa = prelu_a[0];
#pragma unroll
  for (int mi = 0; mi < 4; mi++){
#pragma unroll
    for (int r = 0; r < 4; r++){
      int row = bm + mi*16 + q*4 + r;
      if (row >= M) continue;
#pragma unroll
      for (int nj = 0; nj < 2; nj++){
        int col = bn + wj*32 + nj*16 + l16;
        float v1 = acc1[mi][nj][r] + b1[col];
        v1 = v1 >= 0.f ? v1 : pa * v1;
        float v2 = acc2[mi][nj][r] + b2[col];
        v2 = v2 >= 0.f ? v2 : pa * v2;
        size_t idx = (size_t)row * OUT_C + col;
        hsum[idx]  = f2b(v1 + v2);
        hdiff[idx] = f2b(v1 - v2);
      }
    }
  }
}

// ---------------- GEMM2: 64x128 tiles; colsum += sum_rows tanh(hsum @ Wp1 + bp1) ---------

__global__ __launch_bounds__(256) void gemm2_kernel(const unsigned short* __restrict__ A,
                                                    const unsigned short* __restrict__ BT,
                                                    const float* __restrict__ bp1,
                                                    float* __restrict__ colsum,
                                                    int M, int Mtiles, int perx){
  const int bid = blockIdx.x;
  const int xcd = bid & 7;
  const int li = bid >> 3;
  const int bn_t = li & 7;
  const int bm_t = xcd * perx + (li >> 3);
  if (bm_t >= Mtiles) return;
  const int bm = bm_t * 64, bn = bn_t * 128;
  __shared__ unsigned short Al[64 * 32];
  __shared__ unsigned short Bl[128 * 32];
  __shared__ float cs[128];
  const int t = threadIdx.x;
  const int lane = t & 63, wid = t >> 6;
  const int wj = wid;
  const int l16 = lane & 15, q = lane >> 4;
  const int lch = (lane & 3) * 8;
  if (t < 128) cs[t] = 0.f;
  f32x4 acc[4][2] = {};
  const int arow = bm + wid * 16 + (lane >> 2);
  const int brow0 = bn + wid * 32 + (lane >> 2);
  const int ga = min(arow, M - 1);
  const unsigned short* pa = A + (size_t)ga * OUT_C + lch;
  const unsigned short* pb0 = BT + (size_t)brow0 * OUT_C + lch;
  const unsigned short* pb1 = BT + (size_t)(brow0 + 16) * OUT_C + lch;
  for (int k0 = 0; k0 < OUT_C; k0 += 32){
    GLOAD_LDS16(pa + k0, &Al[(wid * 16) * 32]);
    GLOAD_LDS16(pb0 + k0, &Bl[(wid * 32) * 32]);
    GLOAD_LDS16(pb1 + k0, &Bl[(wid * 32 + 16) * 32]);
    __syncthreads();
    frag8 af[4], bf[2];
#pragma unroll
    for (int mi = 0; mi < 4; mi++) af[mi] = *(const frag8*)&Al[(mi*16 + l16) * 32 + q*8];
#pragma unroll
    for (int nj = 0; nj < 2; nj++) bf[nj] = *(const frag8*)&Bl[(wj*32 + nj*16 + l16) * 32 + q*8];
#pragma unroll
    for (int mi = 0; mi < 4; mi++)
#pragma unroll
      for (int nj = 0; nj < 2; nj++)
        acc[mi][nj] = __builtin_amdgcn_mfma_f32_16x16x32_bf16(af[mi], bf[nj], acc[mi][nj], 0, 0, 0);
    __syncthreads();
  }
#pragma unroll
  for (int nj = 0; nj < 2; nj++){
    int col = bn + wj*32 + nj*16 + l16;
    float bias = bp1[col];
    float p = 0.f;
#pragma unroll
    for (int mi = 0; mi < 4; mi++){
#pragma unroll
      for (int r = 0; r < 4; r++){
        int row = bm + mi*16 + q*4 + r;
        float tv = tanhf(acc[mi][nj][r] + bias);
        if (row < M) p += tv;
      }
    }
    p += __shfl_xor(p, 16);
    p += __shfl_xor(p, 32);
    if (q == 0) atomicAdd(&cs[wj*32 + nj*16 + l16], p);
  }
  __syncthreads();
  if (t < 128) atomicAdd(&colsum[bn + t], cs[t]);
}

// ---------------- semantic attention tail ----------------

__global__ void wproj_kernel(const float* __restrict__ colsum, const float* __restrict__ Wp2,
                             float* __restrict__ wv){
  int o = blockIdx.x * 256 + threadIdx.x;
  int c0 = blockIdx.y * 128;
  float acc = 0.f;
  for (int c = c0; c < c0 + 128; c++) acc += colsum[c] * Wp2[(size_t)c * OUT_C + o];
  atomicAdd(&wv[o], acc);
}

__global__ __launch_bounds__(1024) void softmax_kernel(const float* __restrict__ wv,
                                                       float* __restrict__ att, float invN){
  int o = threadIdx.x;
  __shared__ float red[1024];
  float w = wv[o] * invN;
  red[o] = w; __syncthreads();
  for (int s = 512; s > 0; s >>= 1){ if (o < s) red[o] = fmaxf(red[o], red[o + s]); __syncthreads(); }
  float m = red[0]; __syncthreads();
  float e = expf(w - m);
  red[o] = e; __syncthreads();
  for (int s = 512; s > 0; s >>= 1){ if (o < s) red[o] += red[o + s]; __syncthreads(); }
  att[o] = e / red[0];
}

__global__ void combine_kernel(const float* __restrict__ att, const unsigned short* __restrict__ hs,
                               const unsigned short* __restrict__ hd, float* __restrict__ out, int total8){
  int i = blockIdx.x * 256 + threadIdx.x;
  if (i >= total8) return;
  int colb = (i & 127) * 8;
  int4 us = ((const int4*)hs)[i];
  int4 ud = ((const int4*)hd)[i];
  float4 a0 = *(const float4*)(att + colb);
  float4 a1 = *(const float4*)(att + colb + 4);
  float o[8]; float sv, dv;
  sv = __uint_as_float(((unsigned)us.x) << 16);        dv = __uint_as_float(((unsigned)ud.x) << 16);
  o[0] = 0.5f * sv + (a0.x - 0.5f) * dv;
  sv = __uint_as_float(((unsigned)us.x) & 0xffff0000u); dv = __uint_as_float(((unsigned)ud.x) & 0xffff0000u);
  o[1] = 0.5f * sv + (a0.y - 0.5f) * dv;
  sv = __uint_as_float(((unsigned)us.y) << 16);        dv = __uint_as_float(((unsigned)ud.y) << 16);
  o[2] = 0.5f * sv + (a0.z - 0.5f) * dv;
  sv = __uint_as_float(((unsigned)us.y) & 0xffff0000u); dv = __uint_as_float(((unsigned)ud.y) & 0xffff0000u);
  o[3] = 0.5f * sv + (a0.w - 0.5f) * dv;
  sv = __uint_as_float(((unsigned)us.z) << 16);        dv = __uint_as_float(((unsigned)ud.z) << 16);
  o[4] = 0.5f * sv + (a1.x - 0.5f) * dv;
  sv = __uint_as_float(((unsigned)us.z) & 0xffff0000u); dv = __uint_as_float(((unsigned)ud.z) & 0xffff0000u);
  o[5] = 0.5f * sv + (a1.y - 0.5f) * dv;
  sv = __uint_as_float(((unsigned)us.w) << 16);        dv = __uint_as_float(((unsigned)ud.w) << 16);
  o[6] = 0.5f * sv + (a1.z - 0.5f) * dv;
  sv = __uint_as_float(((unsigned)us.w) & 0xffff0000u); dv = __uint_as_float(((unsigned)ud.w) & 0xffff0000u);
  o[7] = 0.5f * sv + (a1.w - 0.5f) * dv;
  float4 f0; f0.x = o[0]; f0.y = o[1]; f0.z = o[2]; f0.w = o[3];
  float4 f1; f1.x = o[4]; f1.y = o[5]; f1.z = o[6]; f1.w = o[7];
  *(float4*)(out + (size_t)i * 8) = f0;
  *(float4*)(out + (size_t)i * 8 + 4) = f1;
}

// ---------------- launch ----------------

extern "C" void kernel_launch(void* const* d_in, const int* in_sizes, int n_in,
                              void* d_out, int out_size, void* d_ws, size_t ws_size,
                              hipStream_t stream){
  const float* x      = (const float*)d_in[0];
  const int*   edge   = (const int*)d_in[1];
  const float* W1     = (const float*)d_in[2];
  const float* a_src1 = (const float*)d_in[3];
  const float* a_dst1 = (const float*)d_in[4];
  const float* b1     = (const float*)d_in[5];
  const float* W2     = (const float*)d_in[6];
  const float* a_src2 = (const float*)d_in[7];
  const float* a_dst2 = (const float*)d_in[8];
  const float* b2     = (const float*)d_in[9];
  const float* prelu_a= (const float*)d_in[10];
  const float* Wp1    = (const float*)d_in[11];
  const float* bp1    = (const float*)d_in[12];
  const float* Wp2    = (const float*)d_in[13];
  const int N = in_sizes[0] / IN_C;
  const int E = in_sizes[1] / 2;
  const int* srcArr = edge;
  const int* dstArr = edge + E;

  char* ws = (char*)d_ws;
  size_t o = 0;
  auto alloc = [&](size_t b) -> char* {
    char* p = ws + o;
    o = (o + b + 255) & ~(size_t)255;
    return p;
  };
  unsigned short* xb    = (unsigned short*)alloc((size_t)N * IN_C * 2);
  unsigned short* WT    = (unsigned short*)alloc((size_t)NC2 * IN_C * 2);
  unsigned short* Wp1T  = (unsigned short*)alloc((size_t)OUT_C * OUT_C * 2);
  unsigned short* xa1b  = (unsigned short*)alloc((size_t)N * IN_C * 2);
  unsigned short* xa2b  = (unsigned short*)alloc((size_t)N * IN_C * 2);
  unsigned short* hsum  = (unsigned short*)alloc((size_t)N * OUT_C * 2);
  unsigned short* hdiff = (unsigned short*)alloc((size_t)N * OUT_C * 2);
  float*          uv    = (float*)alloc(4 * IN_C * 4);
  float*          as1   = (float*)alloc((size_t)4 * N * 4);
  float* ad1 = as1 + N; float* as2 = as1 + 2 * N; float* ad2 = as1 + 3 * N;
  float*          self1 = (float*)alloc((size_t)2 * N * 4); float* self2 = self1 + N;
  unsigned*       m1e   = (unsigned*)alloc((size_t)2 * N * 4); unsigned* m2e = m1e + N;
  float*          m1    = (float*)alloc((size_t)2 * N * 4); float* m2 = m1 + N;
  float*          den1  = (float*)alloc((size_t)2 * N * 4); float* den2 = den1 + N;
  int*            counts= (int*)alloc((size_t)N * 4);
  int*            offs  = (int*)alloc((size_t)(N + 1) * 4);
  int*            cursor= (int*)alloc((size_t)N * 4);
  int*            bsum  = (int*)alloc(64 * 4);
  int*            nsrc  = (int*)alloc((size_t)E * 4);
  float*          nw1   = (float*)alloc((size_t)E * 4);
  float*          nw2   = (float*)alloc((size_t)E * 4);
  float*          colsum= (float*)alloc(OUT_C * 4);
  float*          wv    = (float*)alloc(OUT_C * 4);
  float*          att   = (float*)alloc(OUT_C * 4);

  const int Mtiles = (N + 63) / 64;
  const int perx = (Mtiles + 7) / 8;
  const int gemmgrid = 8 * perx * 8;
  const int nchunk = (N + 255) / 256;

  prep_kernel<<<2560, 256, 0, stream>>>(W1, W2, Wp1, a_src1, a_dst1, a_src2, a_dst2, WT, Wp1T, uv);
  alpha_kernel<<<N, 256, 0, stream>>>(x, uv, xb, as1, ad1, as2, ad2, self1, self2, m1e, m2e,
                                      counts, cursor, colsum, wv);
  histmax_kernel<<<(E + 255) / 256, 256, 0, stream>>>(srcArr, dstArr, as1, ad1, as2, ad2,
                                                      counts, m1e, m2e, E);
  scanA_kernel<<<nchunk, 256, 0, stream>>>(counts, offs, bsum, N);
  scanB_kernel<<<1, 64, 0, stream>>>(bsum, nchunk);
  scanC_kernel<<<nchunk, 256, 0, stream>>>(offs, bsum, N);
  denominit_kernel<<<nchunk, 256, 0, stream>>>(m1e, m2e, self1, self2, m1, m2, den1, den2, N);
  scatterexp_kernel<<<(E + 255) / 256, 256, 0, stream>>>(srcArr, dstArr, offs, cursor,
                                                         as1, ad1, as2, ad2, m1, m2,
                                                         nsrc, nw1, nw2, den1, den2, E);
  aggx_kernel<<<dim3(4, (N + 15) / 16), 256, 0, stream>>>(counts, offs, nsrc, nw1, nw2, den1, den2,
                                                          self1, self2, m1, m2, xb, xa1b, xa2b, N);
  gemmh_kernel<<<gemmgrid, 256, 0, stream>>>(xa1b, xa2b, WT, b1, b2, prelu_a,
                                             hsum, hdiff, N, Mtiles, perx);
  gemm2_kernel<<<gemmgrid, 256, 0, stream>>>(hsum, Wp1T, bp1, colsum, N, Mtiles, perx);
  wproj_kernel<<<dim3(4, 8), 256, 0, stream>>>(colsum, Wp2, wv);
  softmax_kernel<<<1, 1024, 0, stream>>>(wv, att, 1.0f / (float)N);
  combine_kernel<<<(N * OUT_C / 8 + 255) / 256, 256, 0, stream>>>(att, hsum, hdiff, (float*)d_out,
                                                                  N * OUT_C / 8);
}